// Round 6
// baseline (610.959 us; speedup 1.0000x reference)
//
#include <hip/hip_runtime.h>
#include <hip/hip_bf16.h>
#include <math.h>

#define N_NODES 50000
#define IN_CH   128
#define HID     64
#define HEADS   4
#define OUT_CH  16
#define NE      800000
#define ETOT    (NE + N_NODES)
#define NEG_SLOPE 0.2f

// ---------------------------------------------------------------------------
// GEMM1: xlxr1[n][m] = sum_k x[n][k]*Wcat[k][m], Wcat=[W1l|W1r], m<512.
// One block = 64 rows x ALL 512 cols; x staged once, W staged per 64-col tile.
// Also zero-fills counts[] (replaces a memset dispatch).
// ---------------------------------------------------------------------------
__global__ __launch_bounds__(256) void k_gemm1(const float* __restrict__ x,
        const float* __restrict__ Wl, const float* __restrict__ Wr,
        float* __restrict__ out, int* __restrict__ counts) {
    int tid = threadIdx.x;
    int zi = blockIdx.x * 256 + tid;
    if (zi < N_NODES) counts[zi] = 0;

    __shared__ float xs[64][132];
    __shared__ float ws[128][64];
    int rb = blockIdx.x * 64;
    // stage x tile once: 64 rows x 128 cols (2048 float4)
    for (int i = 0; i < 8; ++i) {
        int idx = i * 256 + tid;
        int r = idx >> 5, c4 = idx & 31;
        float4 v = make_float4(0.f, 0.f, 0.f, 0.f);
        int gr = rb + r;
        if (gr < N_NODES) v = *(const float4*)(x + (size_t)gr * IN_CH + c4 * 4);
        *(float4*)&xs[r][c4 * 4] = v;
    }
    int cg = tid & 15, rg = tid >> 4;
    int c0 = cg * 4, r0 = rg * 4;

    for (int ct = 0; ct < 8; ++ct) {
        int cb = ct * 64;
        const float* W = (ct < 4) ? Wl : Wr;
        int wc = cb & 255;
        __syncthreads();   // first iter: xs ready; later: readers done with ws
        for (int i = 0; i < 8; ++i) {
            int idx = i * 256 + tid;
            int r = idx >> 4, c4 = idx & 15;
            *(float4*)&ws[r][c4 * 4] = *(const float4*)(W + (size_t)r * 256 + wc + c4 * 4);
        }
        __syncthreads();

        float acc[4][4];
        #pragma unroll
        for (int i = 0; i < 4; ++i)
            #pragma unroll
            for (int j = 0; j < 4; ++j) acc[i][j] = 0.f;
        for (int k = 0; k < 128; ++k) {
            float xv[4];
            #pragma unroll
            for (int i = 0; i < 4; ++i) xv[i] = xs[r0 + i][k];
            float4 wv = *(float4*)&ws[k][c0];
            #pragma unroll
            for (int i = 0; i < 4; ++i) {
                acc[i][0] += xv[i] * wv.x;
                acc[i][1] += xv[i] * wv.y;
                acc[i][2] += xv[i] * wv.z;
                acc[i][3] += xv[i] * wv.w;
            }
        }
        #pragma unroll
        for (int i = 0; i < 4; ++i) {
            int gr = rb + r0 + i;
            if (gr < N_NODES) {
                float4 v = make_float4(acc[i][0], acc[i][1], acc[i][2], acc[i][3]);
                *(float4*)(out + (size_t)gr * 512 + cb + c0) = v;
            }
        }
    }
}

// ---------------------------------------------------------------------------
// CSR build (bucket by dst): count -> single-block scan -> fill
// ---------------------------------------------------------------------------
__global__ void k_count(const int* __restrict__ ei, int* __restrict__ counts) {
    int e = blockIdx.x * blockDim.x + threadIdx.x;
    if (e >= ETOT) return;
    int dst = (e < NE) ? ei[NE + e] : (e - NE);
    atomicAdd(&counts[dst], 1);
}

#define SCAN_T 1024
__global__ __launch_bounds__(SCAN_T) void k_scan(const int* __restrict__ counts,
        int* __restrict__ rowptr, int* __restrict__ cursor) {
    __shared__ int lds[SCAN_T];
    int t = threadIdx.x;
    const int C = (N_NODES + SCAN_T - 1) / SCAN_T;   // 49
    int b = t * C;
    int e = b + C; if (e > N_NODES) e = N_NODES;
    int sum = 0;
    for (int i = b; i < e; ++i) sum += counts[i];
    lds[t] = sum;
    __syncthreads();
    int val = sum;
    for (int off = 1; off < SCAN_T; off <<= 1) {
        int tv = (t >= off) ? lds[t - off] : 0;
        __syncthreads();
        val += tv;
        lds[t] = val;
        __syncthreads();
    }
    int run = val - sum;   // exclusive prefix of this chunk
    for (int i = b; i < e; ++i) {
        rowptr[i] = run;
        cursor[i] = run;
        run += counts[i];
    }
    if (b < N_NODES && e == N_NODES) rowptr[N_NODES] = run;
}

__global__ void k_fill(const int* __restrict__ ei, int* __restrict__ cursor,
        int* __restrict__ csrc) {
    int e = blockIdx.x * blockDim.x + threadIdx.x;
    if (e >= ETOT) return;
    int src, dst;
    if (e < NE) { src = ei[e]; dst = ei[NE + e]; }
    else        { src = e - NE; dst = src; }
    int pos = atomicAdd(&cursor[dst], 1);
    csrc[pos] = src;
}

// ---------------------------------------------------------------------------
// Layer-1 aggregation. lane -> (head = lane>>4, chans = (lane&15)*4 .. +3).
// 4-edge unrolled: 4 float4 gathers in flight, batched shuffles, sequential
// online-softmax merges. Fused bias+ELU epilogue.
// ---------------------------------------------------------------------------
__device__ __forceinline__ float edge_logit(float4 xl, float4 xr, float4 av) {
    float4 u;
    u.x = xl.x + xr.x; u.y = xl.y + xr.y; u.z = xl.z + xr.z; u.w = xl.w + xr.w;
    u.x = (u.x > 0.f) ? u.x : u.x * NEG_SLOPE;
    u.y = (u.y > 0.f) ? u.y : u.y * NEG_SLOPE;
    u.z = (u.z > 0.f) ? u.z : u.z * NEG_SLOPE;
    u.w = (u.w > 0.f) ? u.w : u.w * NEG_SLOPE;
    return u.x * av.x + u.y * av.y + u.z * av.z + u.w * av.w;
}

__device__ __forceinline__ void sm_update(float t, float4 xv,
        float& m, float& s, float4& acc) {
    float nm = fmaxf(m, t);
    float sc = __expf(m - nm), p = __expf(t - nm);
    s = s * sc + p;
    acc.x = acc.x * sc + p * xv.x;
    acc.y = acc.y * sc + p * xv.y;
    acc.z = acc.z * sc + p * xv.z;
    acc.w = acc.w * sc + p * xv.w;
    m = nm;
}

__global__ __launch_bounds__(256) void k_agg1(const float* __restrict__ xlxr,
        const int* __restrict__ rowptr, const int* __restrict__ csrc,
        const float* __restrict__ att, const float* __restrict__ b1,
        float* __restrict__ h) {
    int wave = threadIdx.x >> 6, lane = threadIdx.x & 63;
    int d = blockIdx.x * 4 + wave;
    if (d >= N_NODES) return;
    int hh = lane >> 4, cb = (lane & 15) * 4;
    int co = hh * 64 + cb;
    const float* base_l = xlxr + co;
    float4 xr = *(const float4*)(xlxr + (size_t)d * 512 + 256 + co);
    float4 av = *(const float4*)(att + co);
    float m = -1e30f, s = 0.f;
    float4 acc = make_float4(0.f, 0.f, 0.f, 0.f);
    int e0 = rowptr[d], e1 = rowptr[d + 1];
    int i = e0;
    for (; i + 3 < e1; i += 4) {
        int s0 = csrc[i], s1 = csrc[i + 1], s2 = csrc[i + 2], s3 = csrc[i + 3];
        float4 x0 = *(const float4*)(base_l + (size_t)s0 * 512);
        float4 x1 = *(const float4*)(base_l + (size_t)s1 * 512);
        float4 x2 = *(const float4*)(base_l + (size_t)s2 * 512);
        float4 x3 = *(const float4*)(base_l + (size_t)s3 * 512);
        float t0 = edge_logit(x0, xr, av);
        float t1 = edge_logit(x1, xr, av);
        float t2 = edge_logit(x2, xr, av);
        float t3 = edge_logit(x3, xr, av);
        #pragma unroll
        for (int off = 8; off >= 1; off >>= 1) {
            t0 += __shfl_xor(t0, off, 64);
            t1 += __shfl_xor(t1, off, 64);
            t2 += __shfl_xor(t2, off, 64);
            t3 += __shfl_xor(t3, off, 64);
        }
        sm_update(t0, x0, m, s, acc);
        sm_update(t1, x1, m, s, acc);
        sm_update(t2, x2, m, s, acc);
        sm_update(t3, x3, m, s, acc);
    }
    for (; i < e1; ++i) {
        int s0 = csrc[i];
        float4 x0 = *(const float4*)(base_l + (size_t)s0 * 512);
        float t0 = edge_logit(x0, xr, av);
        #pragma unroll
        for (int off = 8; off >= 1; off >>= 1) t0 += __shfl_xor(t0, off, 64);
        sm_update(t0, x0, m, s, acc);
    }
    float inv = 1.f / s;
    float4 bv = *(const float4*)(b1 + co);
    float4 v;
    v.x = acc.x * inv + bv.x;
    v.y = acc.y * inv + bv.y;
    v.z = acc.z * inv + bv.z;
    v.w = acc.w * inv + bv.w;
    v.x = (v.x > 0.f) ? v.x : (__expf(v.x) - 1.f);
    v.y = (v.y > 0.f) ? v.y : (__expf(v.y) - 1.f);
    v.z = (v.z > 0.f) ? v.z : (__expf(v.z) - 1.f);
    v.w = (v.w > 0.f) ? v.w : (__expf(v.w) - 1.f);
    *(float4*)(h + (size_t)d * 256 + co) = v;
}

// ---------------------------------------------------------------------------
// GEMM2: W staged once per block; grid-stride loop over node groups.
// ---------------------------------------------------------------------------
__global__ __launch_bounds__(256) void k_gemm2(const float* __restrict__ h,
        const float* __restrict__ W2l, const float* __restrict__ W2r,
        float* __restrict__ out) {
    __shared__ float ws[256 * 32];
    int tid = threadIdx.x;
    for (int i = 0; i < 32; ++i) {
        int idx = i * 256 + tid;
        int k = idx >> 5, mm = idx & 31;
        ws[idx] = (mm < 16) ? W2l[k * 16 + mm] : W2r[k * 16 + (mm - 16)];
    }
    __syncthreads();
    int wave = tid >> 6, lane = tid & 63;
    int mm = lane & 31, kh = lane >> 5;
    for (int n = blockIdx.x * 4 + wave; n < N_NODES; n += gridDim.x * 4) {
        float acc = 0.f;
        const float* hp = h + (size_t)n * 256 + kh * 128;
        #pragma unroll
        for (int kk4 = 0; kk4 < 32; ++kk4) {
            float4 hv = *(const float4*)(hp + kk4 * 4);
            int kb = (kh * 128 + kk4 * 4) * 32 + mm;
            acc += hv.x * ws[kb] + hv.y * ws[kb + 32] + hv.z * ws[kb + 64] + hv.w * ws[kb + 96];
        }
        acc += __shfl_xor(acc, 32, 64);
        if (lane < 32) out[(size_t)n * 32 + mm] = acc;
    }
}

// ---------------------------------------------------------------------------
// Layer-2 aggregation: 4 edges per wave-iteration, 16 lanes each; merge the 4
// online-softmax partials at the end via xor-16/32 shuffles.
// ---------------------------------------------------------------------------
__global__ __launch_bounds__(256) void k_agg2(const float* __restrict__ xlxr2,
        const int* __restrict__ rowptr, const int* __restrict__ csrc,
        const float* __restrict__ att2, const float* __restrict__ b2,
        float* __restrict__ out) {
    int wave = threadIdx.x >> 6, lane = threadIdx.x & 63;
    int d = blockIdx.x * 4 + wave;
    if (d >= N_NODES) return;
    int g = lane >> 4, c = lane & 15;
    float xrv = xlxr2[(size_t)d * 32 + 16 + c];
    float a   = att2[c];
    float m = -1e30f, s = 0.f, acc = 0.f;
    int e0 = rowptr[d], e1 = rowptr[d + 1];
    for (int i = e0 + g; i < e1; i += 4) {
        int src = csrc[i];
        float xl = xlxr2[(size_t)src * 32 + c];
        float u = xl + xrv;
        u = (u > 0.f) ? u : u * NEG_SLOPE;
        float t = u * a;
        t += __shfl_xor(t, 8, 64);
        t += __shfl_xor(t, 4, 64);
        t += __shfl_xor(t, 2, 64);
        t += __shfl_xor(t, 1, 64);
        float nm = fmaxf(m, t);
        float sc = __expf(m - nm), p = __expf(t - nm);
        s = s * sc + p;
        acc = acc * sc + p * xl;
        m = nm;
    }
    #pragma unroll
    for (int off = 16; off <= 32; off <<= 1) {
        float mo = __shfl_xor(m, off, 64);
        float so = __shfl_xor(s, off, 64);
        float ao = __shfl_xor(acc, off, 64);
        float nm = fmaxf(m, mo);
        float ea = __expf(m - nm), eb = __expf(mo - nm);
        s   = s * ea + so * eb;
        acc = acc * ea + ao * eb;
        m = nm;
    }
    if (lane < 16) out[(size_t)d * 16 + c] = acc / s + b2[c];
}

// ---------------------------------------------------------------------------
extern "C" void kernel_launch(void* const* d_in, const int* in_sizes, int n_in,
                              void* d_out, int out_size, void* d_ws, size_t ws_size,
                              hipStream_t stream) {
    const float* x    = (const float*)d_in[0];
    const int*   ei   = (const int*)d_in[1];
    const float* W1l  = (const float*)d_in[2];
    const float* W1r  = (const float*)d_in[3];
    const float* att1 = (const float*)d_in[4];
    const float* b1   = (const float*)d_in[5];
    const float* W2l  = (const float*)d_in[6];
    const float* W2r  = (const float*)d_in[7];
    const float* att2 = (const float*)d_in[8];
    const float* b2   = (const float*)d_in[9];
    float* outp = (float*)d_out;

    char* wsb = (char*)d_ws;
    size_t off = 0;
    auto alloc = [&](size_t bytes) {
        void* p = wsb + off;
        off = (off + bytes + 255) & ~(size_t)255;
        return p;
    };
    float* xlxr1 = (float*)alloc((size_t)N_NODES * 512 * 4);
    float* h1    = (float*)alloc((size_t)N_NODES * 256 * 4);
    float* xlxr2 = (float*)alloc((size_t)N_NODES * 32 * 4);
    int* rowptr  = (int*)alloc((N_NODES + 1) * 4);
    int* cursor  = (int*)alloc(N_NODES * 4);
    int* counts  = (int*)alloc(N_NODES * 4);
    int* csrc    = (int*)alloc((size_t)ETOT * 4);

    // gemm1 zero-fills counts (grid 782 blocks x 256 >= 50000 threads)
    k_gemm1<<<(N_NODES + 63) / 64, 256, 0, stream>>>(x, W1l, W1r, xlxr1, counts);

    k_count<<<(ETOT + 255) / 256, 256, 0, stream>>>(ei, counts);
    k_scan<<<1, SCAN_T, 0, stream>>>(counts, rowptr, cursor);
    k_fill<<<(ETOT + 255) / 256, 256, 0, stream>>>(ei, cursor, csrc);

    k_agg1<<<(N_NODES + 3) / 4, 256, 0, stream>>>(xlxr1, rowptr, csrc, att1, b1, h1);
    k_gemm2<<<1280, 256, 0, stream>>>(h1, W2l, W2r, xlxr2);
    k_agg2<<<(N_NODES + 3) / 4, 256, 0, stream>>>(xlxr2, rowptr, csrc, att2, b2, outp);
}

// Round 8
// 585.142 us; speedup vs baseline: 1.0441x; 1.0441x over previous
//
#include <hip/hip_runtime.h>
#include <hip/hip_bf16.h>
#include <math.h>

#define N_NODES 50000
#define IN_CH   128
#define HID     64
#define HEADS   4
#define OUT_CH  16
#define NE      800000
#define ETOT    (NE + N_NODES)
#define NEG_SLOPE 0.2f

// ---------------------------------------------------------------------------
// GEMM1: xlxr1[n][m] = sum_k x[n][k]*Wcat[k][m], Wcat=[W1l|W1r], m<512.
// 64x64 tile per block, K split in two 64-chunks: LDS 33.8KB -> 4 blocks/CU.
// Grid (782, 8) = 6256 blocks -> ~12 residency rounds, ~2% tail.
// Also zero-fills counts[] (replaces a memset dispatch).
// ---------------------------------------------------------------------------
__global__ __launch_bounds__(256) void k_gemm1(const float* __restrict__ x,
        const float* __restrict__ Wl, const float* __restrict__ Wr,
        float* __restrict__ out, int* __restrict__ counts) {
    int tid = threadIdx.x;
    int zi = blockIdx.x * 256 + tid;
    if (zi < N_NODES) counts[zi] = 0;   // racing 0-writes across y-blocks: benign

    __shared__ float xs[64][68];   // +4 pad: column reads spread banks
    __shared__ float ws[64][64];
    int rb = blockIdx.x * 64;
    int cb = blockIdx.y * 64;
    const float* W = (cb < 256) ? Wl : Wr;
    int wc = cb & 255;
    int cg = tid & 15, rg = tid >> 4;
    int c0 = cg * 4, r0 = rg * 4;

    float acc[4][4];
    #pragma unroll
    for (int i = 0; i < 4; ++i)
        #pragma unroll
        for (int j = 0; j < 4; ++j) acc[i][j] = 0.f;

    for (int kc = 0; kc < 2; ++kc) {
        int k0 = kc * 64;
        __syncthreads();   // prior chunk's readers done before overwrite
        // stage xs chunk: 64 rows x 64 cols (1024 float4, 4/thread)
        for (int i = 0; i < 4; ++i) {
            int idx = i * 256 + tid;
            int r = idx >> 4, c4 = idx & 15;
            float4 v = make_float4(0.f, 0.f, 0.f, 0.f);
            int gr = rb + r;
            if (gr < N_NODES) v = *(const float4*)(x + (size_t)gr * IN_CH + k0 + c4 * 4);
            *(float4*)&xs[r][c4 * 4] = v;
        }
        // stage ws chunk: 64 k-rows x 64 cols
        for (int i = 0; i < 4; ++i) {
            int idx = i * 256 + tid;
            int r = idx >> 4, c4 = idx & 15;
            *(float4*)&ws[r][c4 * 4] = *(const float4*)(W + (size_t)(k0 + r) * 256 + wc + c4 * 4);
        }
        __syncthreads();

        for (int k = 0; k < 64; ++k) {
            float xv[4];
            #pragma unroll
            for (int i = 0; i < 4; ++i) xv[i] = xs[r0 + i][k];
            float4 wv = *(float4*)&ws[k][c0];
            #pragma unroll
            for (int i = 0; i < 4; ++i) {
                acc[i][0] += xv[i] * wv.x;
                acc[i][1] += xv[i] * wv.y;
                acc[i][2] += xv[i] * wv.z;
                acc[i][3] += xv[i] * wv.w;
            }
        }
    }
    #pragma unroll
    for (int i = 0; i < 4; ++i) {
        int gr = rb + r0 + i;
        if (gr < N_NODES) {
            float4 v = make_float4(acc[i][0], acc[i][1], acc[i][2], acc[i][3]);
            *(float4*)(out + (size_t)gr * 512 + cb + c0) = v;
        }
    }
}

// ---------------------------------------------------------------------------
// CSR build (bucket by dst): count -> single-block scan -> fill
// ---------------------------------------------------------------------------
__global__ void k_count(const int* __restrict__ ei, int* __restrict__ counts) {
    int e = blockIdx.x * blockDim.x + threadIdx.x;
    if (e >= ETOT) return;
    int dst = (e < NE) ? ei[NE + e] : (e - NE);
    atomicAdd(&counts[dst], 1);
}

#define SCAN_T 1024
__global__ __launch_bounds__(SCAN_T) void k_scan(const int* __restrict__ counts,
        int* __restrict__ rowptr, int* __restrict__ cursor) {
    __shared__ int lds[SCAN_T];
    int t = threadIdx.x;
    const int C = (N_NODES + SCAN_T - 1) / SCAN_T;   // 49
    int b = t * C;
    int e = b + C; if (e > N_NODES) e = N_NODES;
    int sum = 0;
    for (int i = b; i < e; ++i) sum += counts[i];
    lds[t] = sum;
    __syncthreads();
    int val = sum;
    for (int off = 1; off < SCAN_T; off <<= 1) {
        int tv = (t >= off) ? lds[t - off] : 0;
        __syncthreads();
        val += tv;
        lds[t] = val;
        __syncthreads();
    }
    int run = val - sum;   // exclusive prefix of this chunk
    for (int i = b; i < e; ++i) {
        rowptr[i] = run;
        cursor[i] = run;
        run += counts[i];
    }
    if (b < N_NODES && e == N_NODES) rowptr[N_NODES] = run;
}

__global__ void k_fill(const int* __restrict__ ei, int* __restrict__ cursor,
        int* __restrict__ csrc) {
    int e = blockIdx.x * blockDim.x + threadIdx.x;
    if (e >= ETOT) return;
    int src, dst;
    if (e < NE) { src = ei[e]; dst = ei[NE + e]; }
    else        { src = e - NE; dst = src; }
    int pos = atomicAdd(&cursor[dst], 1);
    csrc[pos] = src;
}

// ---------------------------------------------------------------------------
// Layer-1 aggregation. lane -> (head = lane>>4, chans = (lane&15)*4 .. +3).
// 4-edge unrolled: 4 float4 gathers in flight, batched shuffles, sequential
// online-softmax merges. Fused bias+ELU epilogue.
// ---------------------------------------------------------------------------
__device__ __forceinline__ float edge_logit(float4 xl, float4 xr, float4 av) {
    float4 u;
    u.x = xl.x + xr.x; u.y = xl.y + xr.y; u.z = xl.z + xr.z; u.w = xl.w + xr.w;
    u.x = (u.x > 0.f) ? u.x : u.x * NEG_SLOPE;
    u.y = (u.y > 0.f) ? u.y : u.y * NEG_SLOPE;
    u.z = (u.z > 0.f) ? u.z : u.z * NEG_SLOPE;
    u.w = (u.w > 0.f) ? u.w : u.w * NEG_SLOPE;
    return u.x * av.x + u.y * av.y + u.z * av.z + u.w * av.w;
}

__device__ __forceinline__ void sm_update(float t, float4 xv,
        float& m, float& s, float4& acc) {
    float nm = fmaxf(m, t);
    float sc = __expf(m - nm), p = __expf(t - nm);
    s = s * sc + p;
    acc.x = acc.x * sc + p * xv.x;
    acc.y = acc.y * sc + p * xv.y;
    acc.z = acc.z * sc + p * xv.z;
    acc.w = acc.w * sc + p * xv.w;
    m = nm;
}

__global__ __launch_bounds__(256) void k_agg1(const float* __restrict__ xlxr,
        const int* __restrict__ rowptr, const int* __restrict__ csrc,
        const float* __restrict__ att, const float* __restrict__ b1,
        float* __restrict__ h) {
    int wave = threadIdx.x >> 6, lane = threadIdx.x & 63;
    int d = blockIdx.x * 4 + wave;
    if (d >= N_NODES) return;
    int hh = lane >> 4, cb = (lane & 15) * 4;
    int co = hh * 64 + cb;
    const float* base_l = xlxr + co;
    float4 xr = *(const float4*)(xlxr + (size_t)d * 512 + 256 + co);
    float4 av = *(const float4*)(att + co);
    float m = -1e30f, s = 0.f;
    float4 acc = make_float4(0.f, 0.f, 0.f, 0.f);
    int e0 = rowptr[d], e1 = rowptr[d + 1];
    int i = e0;
    for (; i + 3 < e1; i += 4) {
        int s0 = csrc[i], s1 = csrc[i + 1], s2 = csrc[i + 2], s3 = csrc[i + 3];
        float4 x0 = *(const float4*)(base_l + (size_t)s0 * 512);
        float4 x1 = *(const float4*)(base_l + (size_t)s1 * 512);
        float4 x2 = *(const float4*)(base_l + (size_t)s2 * 512);
        float4 x3 = *(const float4*)(base_l + (size_t)s3 * 512);
        float t0 = edge_logit(x0, xr, av);
        float t1 = edge_logit(x1, xr, av);
        float t2 = edge_logit(x2, xr, av);
        float t3 = edge_logit(x3, xr, av);
        #pragma unroll
        for (int off = 8; off >= 1; off >>= 1) {
            t0 += __shfl_xor(t0, off, 64);
            t1 += __shfl_xor(t1, off, 64);
            t2 += __shfl_xor(t2, off, 64);
            t3 += __shfl_xor(t3, off, 64);
        }
        sm_update(t0, x0, m, s, acc);
        sm_update(t1, x1, m, s, acc);
        sm_update(t2, x2, m, s, acc);
        sm_update(t3, x3, m, s, acc);
    }
    for (; i < e1; ++i) {
        int s0 = csrc[i];
        float4 x0 = *(const float4*)(base_l + (size_t)s0 * 512);
        float t0 = edge_logit(x0, xr, av);
        #pragma unroll
        for (int off = 8; off >= 1; off >>= 1) t0 += __shfl_xor(t0, off, 64);
        sm_update(t0, x0, m, s, acc);
    }
    float inv = 1.f / s;
    float4 bv = *(const float4*)(b1 + co);
    float4 v;
    v.x = acc.x * inv + bv.x;
    v.y = acc.y * inv + bv.y;
    v.z = acc.z * inv + bv.z;
    v.w = acc.w * inv + bv.w;
    v.x = (v.x > 0.f) ? v.x : (__expf(v.x) - 1.f);
    v.y = (v.y > 0.f) ? v.y : (__expf(v.y) - 1.f);
    v.z = (v.z > 0.f) ? v.z : (__expf(v.z) - 1.f);
    v.w = (v.w > 0.f) ? v.w : (__expf(v.w) - 1.f);
    *(float4*)(h + (size_t)d * 256 + co) = v;
}

// ---------------------------------------------------------------------------
// GEMM2: W staged once per block; grid-stride loop over node groups.
// ---------------------------------------------------------------------------
__global__ __launch_bounds__(256) void k_gemm2(const float* __restrict__ h,
        const float* __restrict__ W2l, const float* __restrict__ W2r,
        float* __restrict__ out) {
    __shared__ float ws[256 * 32];
    int tid = threadIdx.x;
    for (int i = 0; i < 32; ++i) {
        int idx = i * 256 + tid;
        int k = idx >> 5, mm = idx & 31;
        ws[idx] = (mm < 16) ? W2l[k * 16 + mm] : W2r[k * 16 + (mm - 16)];
    }
    __syncthreads();
    int wave = tid >> 6, lane = tid & 63;
    int mm = lane & 31, kh = lane >> 5;
    for (int n = blockIdx.x * 4 + wave; n < N_NODES; n += gridDim.x * 4) {
        float acc = 0.f;
        const float* hp = h + (size_t)n * 256 + kh * 128;
        #pragma unroll
        for (int kk4 = 0; kk4 < 32; ++kk4) {
            float4 hv = *(const float4*)(hp + kk4 * 4);
            int kb = (kh * 128 + kk4 * 4) * 32 + mm;
            acc += hv.x * ws[kb] + hv.y * ws[kb + 32] + hv.z * ws[kb + 64] + hv.w * ws[kb + 96];
        }
        acc += __shfl_xor(acc, 32, 64);
        if (lane < 32) out[(size_t)n * 32 + mm] = acc;
    }
}

// ---------------------------------------------------------------------------
// Layer-2 aggregation: 4 edges per wave-iteration, 16 lanes each; merge the 4
// online-softmax partials at the end via xor-16/32 shuffles.
// ---------------------------------------------------------------------------
__global__ __launch_bounds__(256) void k_agg2(const float* __restrict__ xlxr2,
        const int* __restrict__ rowptr, const int* __restrict__ csrc,
        const float* __restrict__ att2, const float* __restrict__ b2,
        float* __restrict__ out) {
    int wave = threadIdx.x >> 6, lane = threadIdx.x & 63;
    int d = blockIdx.x * 4 + wave;
    if (d >= N_NODES) return;
    int g = lane >> 4, c = lane & 15;
    float xrv = xlxr2[(size_t)d * 32 + 16 + c];
    float a   = att2[c];
    float m = -1e30f, s = 0.f, acc = 0.f;
    int e0 = rowptr[d], e1 = rowptr[d + 1];
    for (int i = e0 + g; i < e1; i += 4) {
        int src = csrc[i];
        float xl = xlxr2[(size_t)src * 32 + c];
        float u = xl + xrv;
        u = (u > 0.f) ? u : u * NEG_SLOPE;
        float t = u * a;
        t += __shfl_xor(t, 8, 64);
        t += __shfl_xor(t, 4, 64);
        t += __shfl_xor(t, 2, 64);
        t += __shfl_xor(t, 1, 64);
        float nm = fmaxf(m, t);
        float sc = __expf(m - nm), p = __expf(t - nm);
        s = s * sc + p;
        acc = acc * sc + p * xl;
        m = nm;
    }
    #pragma unroll
    for (int off = 16; off <= 32; off <<= 1) {
        float mo = __shfl_xor(m, off, 64);
        float so = __shfl_xor(s, off, 64);
        float ao = __shfl_xor(acc, off, 64);
        float nm = fmaxf(m, mo);
        float ea = __expf(m - nm), eb = __expf(mo - nm);
        s   = s * ea + so * eb;
        acc = acc * ea + ao * eb;
        m = nm;
    }
    if (lane < 16) out[(size_t)d * 16 + c] = acc / s + b2[c];
}

// ---------------------------------------------------------------------------
extern "C" void kernel_launch(void* const* d_in, const int* in_sizes, int n_in,
                              void* d_out, int out_size, void* d_ws, size_t ws_size,
                              hipStream_t stream) {
    const float* x    = (const float*)d_in[0];
    const int*   ei   = (const int*)d_in[1];
    const float* W1l  = (const float*)d_in[2];
    const float* W1r  = (const float*)d_in[3];
    const float* att1 = (const float*)d_in[4];
    const float* b1   = (const float*)d_in[5];
    const float* W2l  = (const float*)d_in[6];
    const float* W2r  = (const float*)d_in[7];
    const float* att2 = (const float*)d_in[8];
    const float* b2   = (const float*)d_in[9];
    float* outp = (float*)d_out;

    char* wsb = (char*)d_ws;
    size_t off = 0;
    auto alloc = [&](size_t bytes) {
        void* p = wsb + off;
        off = (off + bytes + 255) & ~(size_t)255;
        return p;
    };
    float* xlxr1 = (float*)alloc((size_t)N_NODES * 512 * 4);
    float* h1    = (float*)alloc((size_t)N_NODES * 256 * 4);
    float* xlxr2 = (float*)alloc((size_t)N_NODES * 32 * 4);
    int* rowptr  = (int*)alloc((N_NODES + 1) * 4);
    int* cursor  = (int*)alloc(N_NODES * 4);
    int* counts  = (int*)alloc(N_NODES * 4);
    int* csrc    = (int*)alloc((size_t)ETOT * 4);

    dim3 g1((N_NODES + 63) / 64, 8);
    k_gemm1<<<g1, 256, 0, stream>>>(x, W1l, W1r, xlxr1, counts);

    k_count<<<(ETOT + 255) / 256, 256, 0, stream>>>(ei, counts);
    k_scan<<<1, SCAN_T, 0, stream>>>(counts, rowptr, cursor);
    k_fill<<<(ETOT + 255) / 256, 256, 0, stream>>>(ei, cursor, csrc);

    k_agg1<<<(N_NODES + 3) / 4, 256, 0, stream>>>(xlxr1, rowptr, csrc, att1, b1, h1);
    k_gemm2<<<1280, 256, 0, stream>>>(h1, W2l, W2r, xlxr2);
    k_agg2<<<(N_NODES + 3) / 4, 256, 0, stream>>>(xlxr2, rowptr, csrc, att2, b2, outp);
}

// Round 12
// 532.144 us; speedup vs baseline: 1.1481x; 1.0996x over previous
//
#include <hip/hip_runtime.h>
#include <hip/hip_bf16.h>
#include <math.h>

#define N_NODES 50000
#define IN_CH   128
#define HID     64
#define HEADS   4
#define OUT_CH  16
#define NE      800000
#define ETOT    (NE + N_NODES)
#define NEG_SLOPE 0.2f

// f32 -> bf16 (round-to-nearest-even), and back
__device__ __forceinline__ unsigned short f2bf(float f) {
    unsigned int u = __float_as_uint(f);
    u = (u + 0x7FFFu + ((u >> 16) & 1u)) >> 16;
    return (unsigned short)u;
}
__device__ __forceinline__ float bf2f(unsigned short b) {
    return __uint_as_float(((unsigned int)b) << 16);
}

// ---------------------------------------------------------------------------
// GEMM1: [xl | xr] = x @ [W1l | W1r].  xl stored bf16 (gather table),
// xr stored f32. 64x64 tile, split-K staging (33.8KB LDS -> 4 blocks/CU).
// Also zero-fills counts[].
// ---------------------------------------------------------------------------
__global__ __launch_bounds__(256) void k_gemm1(const float* __restrict__ x,
        const float* __restrict__ Wl, const float* __restrict__ Wr,
        unsigned short* __restrict__ xlbf, float* __restrict__ xr1,
        int* __restrict__ counts) {
    int tid = threadIdx.x;
    int zi = blockIdx.x * 256 + tid;
    if (zi < N_NODES) counts[zi] = 0;   // redundant across y-blocks: benign

    __shared__ float xs[64][68];
    __shared__ float ws[64][64];
    int rb = blockIdx.x * 64;
    int cb = blockIdx.y * 64;
    const float* W = (cb < 256) ? Wl : Wr;
    int wc = cb & 255;
    int cg = tid & 15, rg = tid >> 4;
    int c0 = cg * 4, r0 = rg * 4;

    float acc[4][4];
    #pragma unroll
    for (int i = 0; i < 4; ++i)
        #pragma unroll
        for (int j = 0; j < 4; ++j) acc[i][j] = 0.f;

    for (int kc = 0; kc < 2; ++kc) {
        int k0 = kc * 64;
        __syncthreads();
        for (int i = 0; i < 4; ++i) {
            int idx = i * 256 + tid;
            int r = idx >> 4, c4 = idx & 15;
            float4 v = make_float4(0.f, 0.f, 0.f, 0.f);
            int gr = rb + r;
            if (gr < N_NODES) v = *(const float4*)(x + (size_t)gr * IN_CH + k0 + c4 * 4);
            *(float4*)&xs[r][c4 * 4] = v;
        }
        for (int i = 0; i < 4; ++i) {
            int idx = i * 256 + tid;
            int r = idx >> 4, c4 = idx & 15;
            *(float4*)&ws[r][c4 * 4] = *(const float4*)(W + (size_t)(k0 + r) * 256 + wc + c4 * 4);
        }
        __syncthreads();

        for (int k = 0; k < 64; ++k) {
            float xv[4];
            #pragma unroll
            for (int i = 0; i < 4; ++i) xv[i] = xs[r0 + i][k];
            float4 wv = *(float4*)&ws[k][c0];
            #pragma unroll
            for (int i = 0; i < 4; ++i) {
                acc[i][0] += xv[i] * wv.x;
                acc[i][1] += xv[i] * wv.y;
                acc[i][2] += xv[i] * wv.z;
                acc[i][3] += xv[i] * wv.w;
            }
        }
    }
    if (cb < 256) {
        #pragma unroll
        for (int i = 0; i < 4; ++i) {
            int gr = rb + r0 + i;
            if (gr < N_NODES) {
                ushort4 v;
                v.x = f2bf(acc[i][0]); v.y = f2bf(acc[i][1]);
                v.z = f2bf(acc[i][2]); v.w = f2bf(acc[i][3]);
                *(ushort4*)(xlbf + (size_t)gr * 256 + cb + c0) = v;
            }
        }
    } else {
        #pragma unroll
        for (int i = 0; i < 4; ++i) {
            int gr = rb + r0 + i;
            if (gr < N_NODES) {
                float4 v = make_float4(acc[i][0], acc[i][1], acc[i][2], acc[i][3]);
                *(float4*)(xr1 + (size_t)gr * 256 + (cb - 256) + c0) = v;
            }
        }
    }
}

// ---------------------------------------------------------------------------
// CSR build (bucket by dst): count -> single-block scan -> fill
// ---------------------------------------------------------------------------
__global__ void k_count(const int* __restrict__ ei, int* __restrict__ counts) {
    int e = blockIdx.x * blockDim.x + threadIdx.x;
    if (e >= ETOT) return;
    int dst = (e < NE) ? ei[NE + e] : (e - NE);
    atomicAdd(&counts[dst], 1);
}

#define SCAN_T 1024
__global__ __launch_bounds__(SCAN_T) void k_scan(const int* __restrict__ counts,
        int* __restrict__ rowptr, int* __restrict__ cursor) {
    __shared__ int lds[SCAN_T];
    int t = threadIdx.x;
    const int C = (N_NODES + SCAN_T - 1) / SCAN_T;   // 49
    int b = t * C;
    int e = b + C; if (e > N_NODES) e = N_NODES;
    int sum = 0;
    for (int i = b; i < e; ++i) sum += counts[i];
    lds[t] = sum;
    __syncthreads();
    int val = sum;
    for (int off = 1; off < SCAN_T; off <<= 1) {
        int tv = (t >= off) ? lds[t - off] : 0;
        __syncthreads();
        val += tv;
        lds[t] = val;
        __syncthreads();
    }
    int run = val - sum;
    for (int i = b; i < e; ++i) {
        rowptr[i] = run;
        cursor[i] = run;
        run += counts[i];
    }
    if (b < N_NODES && e == N_NODES) rowptr[N_NODES] = run;
}

__global__ void k_fill(const int* __restrict__ ei, int* __restrict__ cursor,
        int* __restrict__ csrc) {
    int e = blockIdx.x * blockDim.x + threadIdx.x;
    if (e >= ETOT) return;
    int src, dst;
    if (e < NE) { src = ei[e]; dst = ei[NE + e]; }
    else        { src = e - NE; dst = src; }
    int pos = atomicAdd(&cursor[dst], 1);
    csrc[pos] = src;
}

// ---------------------------------------------------------------------------
// Layer-1 aggregation. lane -> (head = lane>>4, chans = (lane&15)*4 .. +3).
// xl gathered as bf16 ushort4 (8B/lane, 512B/edge/wave), converted to f32.
// 4-shuffle 16-lane logit reduce, per-lane online softmax, fused bias+ELU.
// ---------------------------------------------------------------------------
__device__ __forceinline__ float edge_logit(float4 xl, float4 xr, float4 av) {
    float4 u;
    u.x = xl.x + xr.x; u.y = xl.y + xr.y; u.z = xl.z + xr.z; u.w = xl.w + xr.w;
    u.x = (u.x > 0.f) ? u.x : u.x * NEG_SLOPE;
    u.y = (u.y > 0.f) ? u.y : u.y * NEG_SLOPE;
    u.z = (u.z > 0.f) ? u.z : u.z * NEG_SLOPE;
    u.w = (u.w > 0.f) ? u.w : u.w * NEG_SLOPE;
    return u.x * av.x + u.y * av.y + u.z * av.z + u.w * av.w;
}

__device__ __forceinline__ void sm_update(float t, float4 xv,
        float& m, float& s, float4& acc) {
    float nm = fmaxf(m, t);
    float sc = __expf(m - nm), p = __expf(t - nm);
    s = s * sc + p;
    acc.x = acc.x * sc + p * xv.x;
    acc.y = acc.y * sc + p * xv.y;
    acc.z = acc.z * sc + p * xv.z;
    acc.w = acc.w * sc + p * xv.w;
    m = nm;
}

__device__ __forceinline__ float4 bf4_to_f4(ushort4 b) {
    return make_float4(bf2f(b.x), bf2f(b.y), bf2f(b.z), bf2f(b.w));
}

__global__ __launch_bounds__(256) void k_agg1(
        const unsigned short* __restrict__ xlbf, const float* __restrict__ xr1,
        const int* __restrict__ rowptr, const int* __restrict__ csrc,
        const float* __restrict__ att, const float* __restrict__ b1,
        float* __restrict__ h) {
    int wave = threadIdx.x >> 6, lane = threadIdx.x & 63;
    int d = blockIdx.x * 4 + wave;
    if (d >= N_NODES) return;
    int hh = lane >> 4, cb = (lane & 15) * 4;
    int co = hh * 64 + cb;
    const unsigned short* base_l = xlbf + co;
    float4 xr = *(const float4*)(xr1 + (size_t)d * 256 + co);
    float4 av = *(const float4*)(att + co);
    float m = -1e30f, s = 0.f;
    float4 acc = make_float4(0.f, 0.f, 0.f, 0.f);
    int e0 = rowptr[d], e1 = rowptr[d + 1];
    int i = e0;
    for (; i + 3 < e1; i += 4) {
        int s0 = csrc[i], s1 = csrc[i + 1], s2 = csrc[i + 2], s3 = csrc[i + 3];
        float4 x0 = bf4_to_f4(*(const ushort4*)(base_l + (size_t)s0 * 256));
        float4 x1 = bf4_to_f4(*(const ushort4*)(base_l + (size_t)s1 * 256));
        float4 x2 = bf4_to_f4(*(const ushort4*)(base_l + (size_t)s2 * 256));
        float4 x3 = bf4_to_f4(*(const ushort4*)(base_l + (size_t)s3 * 256));
        float t0 = edge_logit(x0, xr, av);
        float t1 = edge_logit(x1, xr, av);
        float t2 = edge_logit(x2, xr, av);
        float t3 = edge_logit(x3, xr, av);
        #pragma unroll
        for (int off = 8; off >= 1; off >>= 1) {
            t0 += __shfl_xor(t0, off, 64);
            t1 += __shfl_xor(t1, off, 64);
            t2 += __shfl_xor(t2, off, 64);
            t3 += __shfl_xor(t3, off, 64);
        }
        sm_update(t0, x0, m, s, acc);
        sm_update(t1, x1, m, s, acc);
        sm_update(t2, x2, m, s, acc);
        sm_update(t3, x3, m, s, acc);
    }
    for (; i < e1; ++i) {
        int s0 = csrc[i];
        float4 x0 = bf4_to_f4(*(const ushort4*)(base_l + (size_t)s0 * 256));
        float t0 = edge_logit(x0, xr, av);
        #pragma unroll
        for (int off = 8; off >= 1; off >>= 1) t0 += __shfl_xor(t0, off, 64);
        sm_update(t0, x0, m, s, acc);
    }
    float inv = 1.f / s;
    float4 bv = *(const float4*)(b1 + co);
    float4 v;
    v.x = acc.x * inv + bv.x;
    v.y = acc.y * inv + bv.y;
    v.z = acc.z * inv + bv.z;
    v.w = acc.w * inv + bv.w;
    v.x = (v.x > 0.f) ? v.x : (__expf(v.x) - 1.f);
    v.y = (v.y > 0.f) ? v.y : (__expf(v.y) - 1.f);
    v.z = (v.z > 0.f) ? v.z : (__expf(v.z) - 1.f);
    v.w = (v.w > 0.f) ? v.w : (__expf(v.w) - 1.f);
    *(float4*)(h + (size_t)d * 256 + co) = v;
}

// ---------------------------------------------------------------------------
// GEMM2: W staged once per block; grid-stride loop over node groups.
// ---------------------------------------------------------------------------
__global__ __launch_bounds__(256) void k_gemm2(const float* __restrict__ h,
        const float* __restrict__ W2l, const float* __restrict__ W2r,
        float* __restrict__ out) {
    __shared__ float ws[256 * 32];
    int tid = threadIdx.x;
    for (int i = 0; i < 32; ++i) {
        int idx = i * 256 + tid;
        int k = idx >> 5, mm = idx & 31;
        ws[idx] = (mm < 16) ? W2l[k * 16 + mm] : W2r[k * 16 + (mm - 16)];
    }
    __syncthreads();
    int wave = tid >> 6, lane = tid & 63;
    int mm = lane & 31, kh = lane >> 5;
    for (int n = blockIdx.x * 4 + wave; n < N_NODES; n += gridDim.x * 4) {
        float acc = 0.f;
        const float* hp = h + (size_t)n * 256 + kh * 128;
        #pragma unroll
        for (int kk4 = 0; kk4 < 32; ++kk4) {
            float4 hv = *(const float4*)(hp + kk4 * 4);
            int kb = (kh * 128 + kk4 * 4) * 32 + mm;
            acc += hv.x * ws[kb] + hv.y * ws[kb + 32] + hv.z * ws[kb + 64] + hv.w * ws[kb + 96];
        }
        acc += __shfl_xor(acc, 32, 64);
        if (lane < 32) out[(size_t)n * 32 + mm] = acc;
    }
}

// ---------------------------------------------------------------------------
// Layer-2 aggregation: 4 edges per wave-iteration, 16 lanes each; merge the 4
// online-softmax partials at the end via xor-16/32 shuffles.
// ---------------------------------------------------------------------------
__global__ __launch_bounds__(256) void k_agg2(const float* __restrict__ xlxr2,
        const int* __restrict__ rowptr, const int* __restrict__ csrc,
        const float* __restrict__ att2, const float* __restrict__ b2,
        float* __restrict__ out) {
    int wave = threadIdx.x >> 6, lane = threadIdx.x & 63;
    int d = blockIdx.x * 4 + wave;
    if (d >= N_NODES) return;
    int g = lane >> 4, c = lane & 15;
    float xrv = xlxr2[(size_t)d * 32 + 16 + c];
    float a   = att2[c];
    float m = -1e30f, s = 0.f, acc = 0.f;
    int e0 = rowptr[d], e1 = rowptr[d + 1];
    for (int i = e0 + g; i < e1; i += 4) {
        int src = csrc[i];
        float xl = xlxr2[(size_t)src * 32 + c];
        float u = xl + xrv;
        u = (u > 0.f) ? u : u * NEG_SLOPE;
        float t = u * a;
        t += __shfl_xor(t, 8, 64);
        t += __shfl_xor(t, 4, 64);
        t += __shfl_xor(t, 2, 64);
        t += __shfl_xor(t, 1, 64);
        float nm = fmaxf(m, t);
        float sc = __expf(m - nm), p = __expf(t - nm);
        s = s * sc + p;
        acc = acc * sc + p * xl;
        m = nm;
    }
    #pragma unroll
    for (int off = 16; off <= 32; off <<= 1) {
        float mo = __shfl_xor(m, off, 64);
        float so = __shfl_xor(s, off, 64);
        float ao = __shfl_xor(acc, off, 64);
        float nm = fmaxf(m, mo);
        float ea = __expf(m - nm), eb = __expf(mo - nm);
        s   = s * ea + so * eb;
        acc = acc * ea + ao * eb;
        m = nm;
    }
    if (lane < 16) out[(size_t)d * 16 + c] = acc / s + b2[c];
}

// ---------------------------------------------------------------------------
extern "C" void kernel_launch(void* const* d_in, const int* in_sizes, int n_in,
                              void* d_out, int out_size, void* d_ws, size_t ws_size,
                              hipStream_t stream) {
    const float* x    = (const float*)d_in[0];
    const int*   ei   = (const int*)d_in[1];
    const float* W1l  = (const float*)d_in[2];
    const float* W1r  = (const float*)d_in[3];
    const float* att1 = (const float*)d_in[4];
    const float* b1   = (const float*)d_in[5];
    const float* W2l  = (const float*)d_in[6];
    const float* W2r  = (const float*)d_in[7];
    const float* att2 = (const float*)d_in[8];
    const float* b2   = (const float*)d_in[9];
    float* outp = (float*)d_out;

    char* wsb = (char*)d_ws;
    size_t off = 0;
    auto alloc = [&](size_t bytes) {
        void* p = wsb + off;
        off = (off + bytes + 255) & ~(size_t)255;
        return p;
    };
    unsigned short* xlbf = (unsigned short*)alloc((size_t)N_NODES * 256 * 2); // 25.6 MB
    float* xr1   = (float*)alloc((size_t)N_NODES * 256 * 4);                  // 51.2 MB
    float* h1    = (float*)alloc((size_t)N_NODES * 256 * 4);                  // 51.2 MB
    float* xlxr2 = (float*)alloc((size_t)N_NODES * 32 * 4);
    int* rowptr  = (int*)alloc((N_NODES + 1) * 4);
    int* cursor  = (int*)alloc(N_NODES * 4);
    int* counts  = (int*)alloc(N_NODES * 4);
    int* csrc    = (int*)alloc((size_t)ETOT * 4);

    dim3 g1((N_NODES + 63) / 64, 8);
    k_gemm1<<<g1, 256, 0, stream>>>(x, W1l, W1r, xlbf, xr1, counts);

    k_count<<<(ETOT + 255) / 256, 256, 0, stream>>>(ei, counts);
    k_scan<<<1, SCAN_T, 0, stream>>>(counts, rowptr, cursor);
    k_fill<<<(ETOT + 255) / 256, 256, 0, stream>>>(ei, cursor, csrc);

    k_agg1<<<(N_NODES + 3) / 4, 256, 0, stream>>>(xlbf, xr1, rowptr, csrc, att1, b1, h1);
    k_gemm2<<<1280, 256, 0, stream>>>(h1, W2l, W2r, xlxr2);
    k_agg2<<<(N_NODES + 3) / 4, 256, 0, stream>>>(xlxr2, rowptr, csrc, att2, b2, outp);
}

// Round 13
// 428.637 us; speedup vs baseline: 1.4254x; 1.2415x over previous
//
#include <hip/hip_runtime.h>
#include <hip/hip_bf16.h>
#include <math.h>

#define N_NODES 50000
#define IN_CH   128
#define HID     64
#define HEADS   4
#define OUT_CH  16
#define NE      800000
#define ETOT    (NE + N_NODES)
#define NEG_SLOPE 0.2f

// f32 -> bf16 (round-to-nearest-even), and back
__device__ __forceinline__ unsigned short f2bf(float f) {
    unsigned int u = __float_as_uint(f);
    u = (u + 0x7FFFu + ((u >> 16) & 1u)) >> 16;
    return (unsigned short)u;
}
__device__ __forceinline__ float bf2f(unsigned short b) {
    return __uint_as_float(((unsigned int)b) << 16);
}

// ---------------------------------------------------------------------------
// GEMM1: [xl | xr] = x @ [W1l | W1r].  xl stored bf16 (gather table),
// xr stored f32. 64x64 tile, split-K staging (33.8KB LDS -> 4 blocks/CU).
// Also zero-fills counts[].
// ---------------------------------------------------------------------------
__global__ __launch_bounds__(256) void k_gemm1(const float* __restrict__ x,
        const float* __restrict__ Wl, const float* __restrict__ Wr,
        unsigned short* __restrict__ xlbf, float* __restrict__ xr1,
        int* __restrict__ counts) {
    int tid = threadIdx.x;
    int zi = blockIdx.x * 256 + tid;
    if (zi < N_NODES) counts[zi] = 0;   // redundant across y-blocks: benign

    __shared__ float xs[64][68];
    __shared__ float ws[64][64];
    int rb = blockIdx.x * 64;
    int cb = blockIdx.y * 64;
    const float* W = (cb < 256) ? Wl : Wr;
    int wc = cb & 255;
    int cg = tid & 15, rg = tid >> 4;
    int c0 = cg * 4, r0 = rg * 4;

    float acc[4][4];
    #pragma unroll
    for (int i = 0; i < 4; ++i)
        #pragma unroll
        for (int j = 0; j < 4; ++j) acc[i][j] = 0.f;

    for (int kc = 0; kc < 2; ++kc) {
        int k0 = kc * 64;
        __syncthreads();
        for (int i = 0; i < 4; ++i) {
            int idx = i * 256 + tid;
            int r = idx >> 4, c4 = idx & 15;
            float4 v = make_float4(0.f, 0.f, 0.f, 0.f);
            int gr = rb + r;
            if (gr < N_NODES) v = *(const float4*)(x + (size_t)gr * IN_CH + k0 + c4 * 4);
            *(float4*)&xs[r][c4 * 4] = v;
        }
        for (int i = 0; i < 4; ++i) {
            int idx = i * 256 + tid;
            int r = idx >> 4, c4 = idx & 15;
            *(float4*)&ws[r][c4 * 4] = *(const float4*)(W + (size_t)(k0 + r) * 256 + wc + c4 * 4);
        }
        __syncthreads();

        for (int k = 0; k < 64; ++k) {
            float xv[4];
            #pragma unroll
            for (int i = 0; i < 4; ++i) xv[i] = xs[r0 + i][k];
            float4 wv = *(float4*)&ws[k][c0];
            #pragma unroll
            for (int i = 0; i < 4; ++i) {
                acc[i][0] += xv[i] * wv.x;
                acc[i][1] += xv[i] * wv.y;
                acc[i][2] += xv[i] * wv.z;
                acc[i][3] += xv[i] * wv.w;
            }
        }
    }
    if (cb < 256) {
        #pragma unroll
        for (int i = 0; i < 4; ++i) {
            int gr = rb + r0 + i;
            if (gr < N_NODES) {
                ushort4 v;
                v.x = f2bf(acc[i][0]); v.y = f2bf(acc[i][1]);
                v.z = f2bf(acc[i][2]); v.w = f2bf(acc[i][3]);
                *(ushort4*)(xlbf + (size_t)gr * 256 + cb + c0) = v;
            }
        }
    } else {
        #pragma unroll
        for (int i = 0; i < 4; ++i) {
            int gr = rb + r0 + i;
            if (gr < N_NODES) {
                float4 v = make_float4(acc[i][0], acc[i][1], acc[i][2], acc[i][3]);
                *(float4*)(xr1 + (size_t)gr * 256 + (cb - 256) + c0) = v;
            }
        }
    }
}

// ---------------------------------------------------------------------------
// CSR build (bucket by dst): count -> parallel 3-dispatch scan -> fill
// ---------------------------------------------------------------------------
__global__ void k_count(const int* __restrict__ ei, int* __restrict__ counts) {
    int e = blockIdx.x * blockDim.x + threadIdx.x;
    if (e >= ETOT) return;
    int dst = (e < NE) ? ei[NE + e] : (e - NE);
    atomicAdd(&counts[dst], 1);
}

#define SCAN_T 1024
#define SCAN_B ((N_NODES + SCAN_T - 1) / SCAN_T)   // 49

__global__ __launch_bounds__(SCAN_T) void k_scanA(const int* __restrict__ counts,
        int* __restrict__ tmp, int* __restrict__ bsums) {
    __shared__ int lds[SCAN_T];
    int t = threadIdx.x;
    int i = blockIdx.x * SCAN_T + t;
    int v = (i < N_NODES) ? counts[i] : 0;
    lds[t] = v;
    __syncthreads();
    int val = v;
    for (int off = 1; off < SCAN_T; off <<= 1) {
        int tv = (t >= off) ? lds[t - off] : 0;
        __syncthreads();
        val += tv;
        lds[t] = val;
        __syncthreads();
    }
    if (i < N_NODES) tmp[i] = val;               // inclusive within block
    if (t == SCAN_T - 1) bsums[blockIdx.x] = val;
}

__global__ __launch_bounds__(64) void k_scanB(const int* __restrict__ bsums,
        int* __restrict__ boff) {
    __shared__ int lds[64];
    int t = threadIdx.x;
    int v = (t < SCAN_B) ? bsums[t] : 0;
    lds[t] = v;
    __syncthreads();
    int val = v;
    for (int off = 1; off < 64; off <<= 1) {
        int tv = (t >= off) ? lds[t - off] : 0;
        __syncthreads();
        val += tv;
        lds[t] = val;
        __syncthreads();
    }
    if (t < SCAN_B) boff[t] = val - v;           // exclusive block offset
}

__global__ __launch_bounds__(SCAN_T) void k_scanC(const int* __restrict__ tmp,
        const int* __restrict__ counts, const int* __restrict__ boff,
        int* __restrict__ rowptr, int* __restrict__ cursor) {
    int i = blockIdx.x * SCAN_T + threadIdx.x;
    if (i >= N_NODES) return;
    int c = counts[i];
    int ex = tmp[i] + boff[blockIdx.x] - c;      // exclusive prefix
    rowptr[i] = ex;
    cursor[i] = ex;
    if (i == N_NODES - 1) rowptr[N_NODES] = ex + c;
}

__global__ void k_fill(const int* __restrict__ ei, int* __restrict__ cursor,
        int* __restrict__ csrc) {
    int e = blockIdx.x * blockDim.x + threadIdx.x;
    if (e >= ETOT) return;
    int src, dst;
    if (e < NE) { src = ei[e]; dst = ei[NE + e]; }
    else        { src = e - NE; dst = src; }
    int pos = atomicAdd(&cursor[dst], 1);
    csrc[pos] = src;
}

// ---------------------------------------------------------------------------
// Layer-1 aggregation. lane -> (head = lane>>4, chans = (lane&15)*4 .. +3).
// xl gathered as bf16 ushort4 (8B/lane, 512B/edge/wave), converted to f32.
// 4-shuffle 16-lane logit reduce, per-lane online softmax, fused bias+ELU.
// ---------------------------------------------------------------------------
__device__ __forceinline__ float edge_logit(float4 xl, float4 xr, float4 av) {
    float4 u;
    u.x = xl.x + xr.x; u.y = xl.y + xr.y; u.z = xl.z + xr.z; u.w = xl.w + xr.w;
    u.x = (u.x > 0.f) ? u.x : u.x * NEG_SLOPE;
    u.y = (u.y > 0.f) ? u.y : u.y * NEG_SLOPE;
    u.z = (u.z > 0.f) ? u.z : u.z * NEG_SLOPE;
    u.w = (u.w > 0.f) ? u.w : u.w * NEG_SLOPE;
    return u.x * av.x + u.y * av.y + u.z * av.z + u.w * av.w;
}

__device__ __forceinline__ void sm_update(float t, float4 xv,
        float& m, float& s, float4& acc) {
    float nm = fmaxf(m, t);
    float sc = __expf(m - nm), p = __expf(t - nm);
    s = s * sc + p;
    acc.x = acc.x * sc + p * xv.x;
    acc.y = acc.y * sc + p * xv.y;
    acc.z = acc.z * sc + p * xv.z;
    acc.w = acc.w * sc + p * xv.w;
    m = nm;
}

__device__ __forceinline__ float4 bf4_to_f4(ushort4 b) {
    return make_float4(bf2f(b.x), bf2f(b.y), bf2f(b.z), bf2f(b.w));
}

__global__ __launch_bounds__(256) void k_agg1(
        const unsigned short* __restrict__ xlbf, const float* __restrict__ xr1,
        const int* __restrict__ rowptr, const int* __restrict__ csrc,
        const float* __restrict__ att, const float* __restrict__ b1,
        float* __restrict__ h) {
    int wave = threadIdx.x >> 6, lane = threadIdx.x & 63;
    int d = blockIdx.x * 4 + wave;
    if (d >= N_NODES) return;
    int hh = lane >> 4, cb = (lane & 15) * 4;
    int co = hh * 64 + cb;
    const unsigned short* base_l = xlbf + co;
    float4 xr = *(const float4*)(xr1 + (size_t)d * 256 + co);
    float4 av = *(const float4*)(att + co);
    float m = -1e30f, s = 0.f;
    float4 acc = make_float4(0.f, 0.f, 0.f, 0.f);
    int e0 = rowptr[d], e1 = rowptr[d + 1];
    int i = e0;
    for (; i + 3 < e1; i += 4) {
        int s0 = csrc[i], s1 = csrc[i + 1], s2 = csrc[i + 2], s3 = csrc[i + 3];
        float4 x0 = bf4_to_f4(*(const ushort4*)(base_l + (size_t)s0 * 256));
        float4 x1 = bf4_to_f4(*(const ushort4*)(base_l + (size_t)s1 * 256));
        float4 x2 = bf4_to_f4(*(const ushort4*)(base_l + (size_t)s2 * 256));
        float4 x3 = bf4_to_f4(*(const ushort4*)(base_l + (size_t)s3 * 256));
        float t0 = edge_logit(x0, xr, av);
        float t1 = edge_logit(x1, xr, av);
        float t2 = edge_logit(x2, xr, av);
        float t3 = edge_logit(x3, xr, av);
        #pragma unroll
        for (int off = 8; off >= 1; off >>= 1) {
            t0 += __shfl_xor(t0, off, 64);
            t1 += __shfl_xor(t1, off, 64);
            t2 += __shfl_xor(t2, off, 64);
            t3 += __shfl_xor(t3, off, 64);
        }
        sm_update(t0, x0, m, s, acc);
        sm_update(t1, x1, m, s, acc);
        sm_update(t2, x2, m, s, acc);
        sm_update(t3, x3, m, s, acc);
    }
    for (; i < e1; ++i) {
        int s0 = csrc[i];
        float4 x0 = bf4_to_f4(*(const ushort4*)(base_l + (size_t)s0 * 256));
        float t0 = edge_logit(x0, xr, av);
        #pragma unroll
        for (int off = 8; off >= 1; off >>= 1) t0 += __shfl_xor(t0, off, 64);
        sm_update(t0, x0, m, s, acc);
    }
    float inv = 1.f / s;
    float4 bv = *(const float4*)(b1 + co);
    float4 v;
    v.x = acc.x * inv + bv.x;
    v.y = acc.y * inv + bv.y;
    v.z = acc.z * inv + bv.z;
    v.w = acc.w * inv + bv.w;
    v.x = (v.x > 0.f) ? v.x : (__expf(v.x) - 1.f);
    v.y = (v.y > 0.f) ? v.y : (__expf(v.y) - 1.f);
    v.z = (v.z > 0.f) ? v.z : (__expf(v.z) - 1.f);
    v.w = (v.w > 0.f) ? v.w : (__expf(v.w) - 1.f);
    *(float4*)(h + (size_t)d * 256 + co) = v;
}

// ---------------------------------------------------------------------------
// GEMM2: W staged once per block; grid-stride loop over node groups.
// ---------------------------------------------------------------------------
__global__ __launch_bounds__(256) void k_gemm2(const float* __restrict__ h,
        const float* __restrict__ W2l, const float* __restrict__ W2r,
        float* __restrict__ out) {
    __shared__ float ws[256 * 32];
    int tid = threadIdx.x;
    for (int i = 0; i < 32; ++i) {
        int idx = i * 256 + tid;
        int k = idx >> 5, mm = idx & 31;
        ws[idx] = (mm < 16) ? W2l[k * 16 + mm] : W2r[k * 16 + (mm - 16)];
    }
    __syncthreads();
    int wave = tid >> 6, lane = tid & 63;
    int mm = lane & 31, kh = lane >> 5;
    for (int n = blockIdx.x * 4 + wave; n < N_NODES; n += gridDim.x * 4) {
        float acc = 0.f;
        const float* hp = h + (size_t)n * 256 + kh * 128;
        #pragma unroll
        for (int kk4 = 0; kk4 < 32; ++kk4) {
            float4 hv = *(const float4*)(hp + kk4 * 4);
            int kb = (kh * 128 + kk4 * 4) * 32 + mm;
            acc += hv.x * ws[kb] + hv.y * ws[kb + 32] + hv.z * ws[kb + 64] + hv.w * ws[kb + 96];
        }
        acc += __shfl_xor(acc, 32, 64);
        if (lane < 32) out[(size_t)n * 32 + mm] = acc;
    }
}

// ---------------------------------------------------------------------------
// Layer-2 aggregation: 4 edges per wave-iteration, 16 lanes each; merge the 4
// online-softmax partials at the end via xor-16/32 shuffles.
// ---------------------------------------------------------------------------
__global__ __launch_bounds__(256) void k_agg2(const float* __restrict__ xlxr2,
        const int* __restrict__ rowptr, const int* __restrict__ csrc,
        const float* __restrict__ att2, const float* __restrict__ b2,
        float* __restrict__ out) {
    int wave = threadIdx.x >> 6, lane = threadIdx.x & 63;
    int d = blockIdx.x * 4 + wave;
    if (d >= N_NODES) return;
    int g = lane >> 4, c = lane & 15;
    float xrv = xlxr2[(size_t)d * 32 + 16 + c];
    float a   = att2[c];
    float m = -1e30f, s = 0.f, acc = 0.f;
    int e0 = rowptr[d], e1 = rowptr[d + 1];
    for (int i = e0 + g; i < e1; i += 4) {
        int src = csrc[i];
        float xl = xlxr2[(size_t)src * 32 + c];
        float u = xl + xrv;
        u = (u > 0.f) ? u : u * NEG_SLOPE;
        float t = u * a;
        t += __shfl_xor(t, 8, 64);
        t += __shfl_xor(t, 4, 64);
        t += __shfl_xor(t, 2, 64);
        t += __shfl_xor(t, 1, 64);
        float nm = fmaxf(m, t);
        float sc = __expf(m - nm), p = __expf(t - nm);
        s = s * sc + p;
        acc = acc * sc + p * xl;
        m = nm;
    }
    #pragma unroll
    for (int off = 16; off <= 32; off <<= 1) {
        float mo = __shfl_xor(m, off, 64);
        float so = __shfl_xor(s, off, 64);
        float ao = __shfl_xor(acc, off, 64);
        float nm = fmaxf(m, mo);
        float ea = __expf(m - nm), eb = __expf(mo - nm);
        s   = s * ea + so * eb;
        acc = acc * ea + ao * eb;
        m = nm;
    }
    if (lane < 16) out[(size_t)d * 16 + c] = acc / s + b2[c];
}

// ---------------------------------------------------------------------------
extern "C" void kernel_launch(void* const* d_in, const int* in_sizes, int n_in,
                              void* d_out, int out_size, void* d_ws, size_t ws_size,
                              hipStream_t stream) {
    const float* x    = (const float*)d_in[0];
    const int*   ei   = (const int*)d_in[1];
    const float* W1l  = (const float*)d_in[2];
    const float* W1r  = (const float*)d_in[3];
    const float* att1 = (const float*)d_in[4];
    const float* b1   = (const float*)d_in[5];
    const float* W2l  = (const float*)d_in[6];
    const float* W2r  = (const float*)d_in[7];
    const float* att2 = (const float*)d_in[8];
    const float* b2   = (const float*)d_in[9];
    float* outp = (float*)d_out;

    char* wsb = (char*)d_ws;
    size_t off = 0;
    auto alloc = [&](size_t bytes) {
        void* p = wsb + off;
        off = (off + bytes + 255) & ~(size_t)255;
        return p;
    };
    unsigned short* xlbf = (unsigned short*)alloc((size_t)N_NODES * 256 * 2); // 25.6 MB
    float* xr1   = (float*)alloc((size_t)N_NODES * 256 * 4);                  // 51.2 MB
    float* h1    = (float*)alloc((size_t)N_NODES * 256 * 4);                  // 51.2 MB
    float* xlxr2 = (float*)alloc((size_t)N_NODES * 32 * 4);
    int* rowptr  = (int*)alloc((N_NODES + 1) * 4);
    int* cursor  = (int*)alloc(N_NODES * 4);
    int* counts  = (int*)alloc(N_NODES * 4);
    int* tmp     = (int*)alloc(N_NODES * 4);
    int* bsums   = (int*)alloc(64 * 4);
    int* boff    = (int*)alloc(64 * 4);
    int* csrc    = (int*)alloc((size_t)ETOT * 4);

    dim3 g1((N_NODES + 63) / 64, 8);
    k_gemm1<<<g1, 256, 0, stream>>>(x, W1l, W1r, xlbf, xr1, counts);

    k_count<<<(ETOT + 255) / 256, 256, 0, stream>>>(ei, counts);
    k_scanA<<<SCAN_B, SCAN_T, 0, stream>>>(counts, tmp, bsums);
    k_scanB<<<1, 64, 0, stream>>>(bsums, boff);
    k_scanC<<<SCAN_B, SCAN_T, 0, stream>>>(tmp, counts, boff, rowptr, cursor);
    k_fill<<<(ETOT + 255) / 256, 256, 0, stream>>>(ei, cursor, csrc);

    k_agg1<<<(N_NODES + 3) / 4, 256, 0, stream>>>(xlbf, xr1, rowptr, csrc, att1, b1, h1);
    k_gemm2<<<1280, 256, 0, stream>>>(h1, W2l, W2r, xlxr2);
    k_agg2<<<(N_NODES + 3) / 4, 256, 0, stream>>>(xlxr2, rowptr, csrc, att2, b2, outp);
}